// Round 8
// baseline (115.885 us; speedup 1.0000x reference)
//
#include <hip/hip_runtime.h>

#define N_NODES 50000
#define N_EDGES 800000
#define SCAN_BLK 1024
#define SCAN_NBLK ((N_NODES + SCAN_BLK - 1) / SCAN_BLK)   // 49
#define HB 128                      // histogram blocks
#define CHUNK (N_EDGES / HB)        // 6250 edges per block (exact)
#define EPT ((CHUNK + 1023) / 1024) // 7 edges per thread
#define CNTW (N_NODES / 4)          // 12500 packed u32 = 50 KB LDS

// ---------------------------------------------------------------------------
// node1: 64 nodes/block. Wave w computes output cols j0=8w..8w+7 for 64 nodes.
// Weight indices wave-uniform -> s_load; x staged in LDS (stride 132).
//   sh row = [ x@Wf.T+bf (32) | reg_emb (16) | dep_emb (16) ]
//   p1 = sh @ W1_l.T, r1 = sh @ W1_r.T
// ---------------------------------------------------------------------------
__global__ __launch_bounds__(256) void node1_kernel(
    const float* __restrict__ x, const int* __restrict__ reg_id,
    const int* __restrict__ dep_id,
    const float* __restrict__ W_feat, const float* __restrict__ b_feat,
    const float* __restrict__ reg_emb, const float* __restrict__ dep_emb,
    const float* __restrict__ W1_l, const float* __restrict__ W1_r,
    float* __restrict__ p1, float* __restrict__ r1)
{
    __shared__ float sx[64 * 132];
    __shared__ float sh[64 * 68];

    const int tid = threadIdx.x;
    const int node0 = blockIdx.x * 64;

    for (int i = tid; i < 64 * 32; i += 256) {
        int row = i >> 5, c4 = i & 31;
        float4 v = make_float4(0.f, 0.f, 0.f, 0.f);
        int n = node0 + row;
        if (n < N_NODES) v = *(const float4*)&x[n * 128 + c4 * 4];
        *(float4*)&sx[row * 132 + c4 * 4] = v;
    }
    for (int i = tid; i < 64 * 16; i += 256) {
        int r = i >> 4, f = i & 15;
        int n = node0 + r;
        if (n < N_NODES) {
            sh[r * 68 + 32 + f] = reg_emb[reg_id[n] * 16 + f];
            sh[r * 68 + 48 + f] = dep_emb[dep_id[n] * 16 + f];
        }
    }
    __syncthreads();

    const int nl = tid & 63;
    const int j0 = __builtin_amdgcn_readfirstlane((tid >> 6) * 8);

    {
        float acc[8];
        #pragma unroll
        for (int jj = 0; jj < 8; ++jj) acc[jj] = b_feat[j0 + jj];
        #pragma unroll 4
        for (int k = 0; k < 128; k += 4) {
            float4 xv = *(const float4*)&sx[nl * 132 + k];
            #pragma unroll
            for (int jj = 0; jj < 8; ++jj) {
                const float* wr = &W_feat[(j0 + jj) * 128 + k];
                acc[jj] += xv.x * wr[0] + xv.y * wr[1] + xv.z * wr[2] + xv.w * wr[3];
            }
        }
        #pragma unroll
        for (int jj = 0; jj < 8; ++jj) sh[nl * 68 + j0 + jj] = acc[jj];
    }
    __syncthreads();

    {
        const float* Wbase = (j0 < 16) ? (W1_l + j0 * 64) : (W1_r + (j0 - 16) * 64);
        float acc[8];
        #pragma unroll
        for (int jj = 0; jj < 8; ++jj) acc[jj] = 0.f;
        #pragma unroll 4
        for (int k = 0; k < 64; k += 4) {
            float4 hv = *(const float4*)&sh[nl * 68 + k];
            #pragma unroll
            for (int jj = 0; jj < 8; ++jj) {
                const float* wr = &Wbase[jj * 64 + k];
                acc[jj] += hv.x * wr[0] + hv.y * wr[1] + hv.z * wr[2] + hv.w * wr[3];
            }
        }
        int n = node0 + nl;
        if (n < N_NODES) {
            float* outp = (j0 < 16) ? (p1 + n * 16 + j0) : (r1 + n * 16 + (j0 - 16));
            *(float4*)outp       = make_float4(acc[0], acc[1], acc[2], acc[3]);
            *(float4*)(outp + 4) = make_float4(acc[4], acc[5], acc[6], acc[7]);
        }
    }
}

// ---------------------------------------------------------------------------
// hist_lds: single-pass LDS histogram, packed 8-bit counters (4 nodes/u32),
// NO global atomics. Per-(block,node) count <= ~5 << 255 (CHUNK=6250 over
// 50K nodes), so no byte carry. Writes drank[e] = (dst<<8)|lrank so fill
// never re-reads dst. Counts flushed as packed part[b][w].
// ---------------------------------------------------------------------------
__global__ __launch_bounds__(1024) void hist_lds_kernel(
    const int* __restrict__ ei, unsigned int* __restrict__ part,
    unsigned int* __restrict__ drank)
{
    __shared__ unsigned int cnt[CNTW];   // 50 KB
    const int b  = blockIdx.x;
    const int e0 = b * CHUNK;

    for (int i = threadIdx.x; i < CNTW; i += 1024) cnt[i] = 0u;
    __syncthreads();

    #pragma unroll
    for (int k = 0; k < EPT; ++k) {
        int i = threadIdx.x + k * 1024;
        if (i < CHUNK) {
            int d = ei[N_EDGES + e0 + i];
            unsigned sh = (unsigned)(d & 3) * 8u;
            unsigned old = atomicAdd(&cnt[d >> 2], 1u << sh);
            drank[e0 + i] = ((unsigned)d << 8) | ((old >> sh) & 0xffu);
        }
    }
    __syncthreads();

    for (int i = threadIdx.x; i < CNTW; i += 1024)
        part[b * CNTW + i] = cnt[i];
}

// ---------------------------------------------------------------------------
// bp_kernel: per node i — cross-block exclusive prefix as BYTES
// (bounded by deg <= ~50 << 255) + total degree. Wide grid (196 blocks).
// ---------------------------------------------------------------------------
__global__ __launch_bounds__(256) void bp_kernel(
    const unsigned int* __restrict__ part, unsigned char* __restrict__ bp,
    int* __restrict__ deg)
{
    int i = blockIdx.x * 256 + threadIdx.x;
    if (i >= N_NODES) return;
    int w = i >> 2;
    unsigned sh = (unsigned)(i & 3) * 8u;
    int s = 0;
    #pragma unroll 16
    for (int b = 0; b < HB; ++b) {
        bp[b * N_NODES + i] = (unsigned char)s;
        s += (int)((part[b * CNTW + w] >> sh) & 0xffu);
    }
    deg[i] = s;
}

// ---------------------------------------------------------------------------
// scan1: block-local exclusive scan of deg into rowp1 (+ per-block totals).
// Light: 400 KB total traffic.
// ---------------------------------------------------------------------------
__global__ __launch_bounds__(SCAN_BLK) void scan1_kernel(
    const int* __restrict__ deg, int* __restrict__ rowp1, int* __restrict__ parts)
{
    __shared__ int buf[2][SCAN_BLK];
    int t = threadIdx.x;
    int i = blockIdx.x * SCAN_BLK + t;
    int v = (i < N_NODES) ? deg[i] : 0;
    int cur = 0;
    buf[0][t] = v;
    __syncthreads();
    for (int off = 1; off < SCAN_BLK; off <<= 1) {
        int nv = buf[cur][t] + ((t >= off) ? buf[cur][t - off] : 0);
        buf[cur ^ 1][t] = nv;
        cur ^= 1;
        __syncthreads();
    }
    int incl = buf[cur][t];
    if (i < N_NODES) rowp1[i] = incl - v;          // block-local exclusive
    if (t == SCAN_BLK - 1) parts[blockIdx.x] = incl;
}

// ---------------------------------------------------------------------------
// spoff helper: wave 0 computes the 49-entry exclusive block-offset prefix
// from parts into LDS (~100 cyc; parts is 196 B, L2-broadcast).
// ---------------------------------------------------------------------------
__device__ __forceinline__ void compute_spoff(const int* parts, int* spoff)
{
    if (threadIdx.x < 64) {
        int t = threadIdx.x;
        int orig = (t < SCAN_NBLK) ? parts[t] : 0;
        int v = orig;
        #pragma unroll
        for (int off = 1; off < 64; off <<= 1) {
            int u = __shfl_up(v, off, 64);
            if (t >= off) v += u;
        }
        if (t < SCAN_NBLK) spoff[t] = v - orig;
    }
    __syncthreads();
}

// ---------------------------------------------------------------------------
// fill (atomic-free): pos = rowp1[d] + spoff[d>>10] + bp[b][d] + lrank
// where (d, lrank) come packed in drank[e].
// ---------------------------------------------------------------------------
__global__ __launch_bounds__(256) void fill_kernel(
    const int* __restrict__ ei, const unsigned int* __restrict__ drank,
    const int* __restrict__ rowp1, const int* __restrict__ parts,
    const unsigned char* __restrict__ bp, int* __restrict__ csrc)
{
    __shared__ int spoff[SCAN_NBLK];
    compute_spoff(parts, spoff);

    int t = blockIdx.x * 256 + threadIdx.x;
    if (t < N_EDGES) {
        unsigned pr = drank[t];
        int d = (int)(pr >> 8);
        int b = t / CHUNK;
        int pos = rowp1[d] + spoff[d >> 10] + (int)bp[b * N_NODES + d]
                + (int)(pr & 0xffu);
        csrc[pos] = ei[t];
    }
}

// ---------------------------------------------------------------------------
// gather1: one wave per node; 16 edge slots x float4; butterfly reduce;
// slot 0 applies mean + bias + residual + relu.
// ---------------------------------------------------------------------------
__global__ __launch_bounds__(256) void gather1_kernel(
    const int* __restrict__ rowp1, const int* __restrict__ parts,
    const int* __restrict__ csrc,
    const float* __restrict__ p1, const float* __restrict__ r1,
    const float* __restrict__ b1_l, float* __restrict__ h1)
{
    __shared__ int spoff[SCAN_NBLK];
    compute_spoff(parts, spoff);

    int n = (blockIdx.x * 256 + threadIdx.x) >> 6;
    if (n >= N_NODES) return;
    int lane = threadIdx.x & 63;
    int slot = lane >> 2, f4 = lane & 3;
    int start = rowp1[n] + spoff[n >> 10];
    int end = (n + 1 < N_NODES) ? rowp1[n + 1] + spoff[(n + 1) >> 10] : N_EDGES;

    float4 acc = make_float4(0.f, 0.f, 0.f, 0.f);
    for (int e0 = start; e0 < end; e0 += 16) {
        int e = e0 + slot;
        if (e < end) {
            float4 v = *(const float4*)&p1[csrc[e] * 16 + f4 * 4];
            acc.x += v.x; acc.y += v.y; acc.z += v.z; acc.w += v.w;
        }
    }
    #pragma unroll
    for (int off = 4; off <= 32; off <<= 1) {
        acc.x += __shfl_xor(acc.x, off, 64);
        acc.y += __shfl_xor(acc.y, off, 64);
        acc.z += __shfl_xor(acc.z, off, 64);
        acc.w += __shfl_xor(acc.w, off, 64);
    }
    if (slot == 0) {
        float inv = 1.0f / fmaxf((float)(end - start), 1.0f);
        float4 rv = *(const float4*)&r1[n * 16 + f4 * 4];
        float4 bv = *(const float4*)&b1_l[f4 * 4];
        float4 o;
        o.x = fmaxf(acc.x * inv + bv.x + rv.x, 0.f);
        o.y = fmaxf(acc.y * inv + bv.y + rv.y, 0.f);
        o.z = fmaxf(acc.z * inv + bv.z + rv.z, 0.f);
        o.w = fmaxf(acc.w * inv + bv.w + rv.w, 0.f);
        *(float4*)&h1[n * 16 + f4 * 4] = o;
    }
}

// ---------------------------------------------------------------------------
// gather2 + node2 + final, fused. One wave per node.
// ---------------------------------------------------------------------------
__global__ __launch_bounds__(256) void gather2_kernel(
    const int* __restrict__ rowp1, const int* __restrict__ parts,
    const int* __restrict__ csrc, const float* __restrict__ h1,
    const float* __restrict__ W2_l, const float* __restrict__ b2_l,
    const float* __restrict__ W2_r, const float* __restrict__ W_lin,
    const float* __restrict__ b_lin, float* __restrict__ out)
{
    __shared__ int spoff[SCAN_NBLK];
    compute_spoff(parts, spoff);

    int n = (blockIdx.x * 256 + threadIdx.x) >> 6;
    if (n >= N_NODES) return;
    int lane = threadIdx.x & 63;
    int slot = lane >> 2, f4 = lane & 3;
    int start = rowp1[n] + spoff[n >> 10];
    int end = (n + 1 < N_NODES) ? rowp1[n + 1] + spoff[(n + 1) >> 10] : N_EDGES;

    float4 acc = make_float4(0.f, 0.f, 0.f, 0.f);
    for (int e0 = start; e0 < end; e0 += 16) {
        int e = e0 + slot;
        if (e < end) {
            float4 v = *(const float4*)&h1[csrc[e] * 16 + f4 * 4];
            acc.x += v.x; acc.y += v.y; acc.z += v.z; acc.w += v.w;
        }
    }
    #pragma unroll
    for (int off = 4; off <= 32; off <<= 1) {
        acc.x += __shfl_xor(acc.x, off, 64);
        acc.y += __shfl_xor(acc.y, off, 64);
        acc.z += __shfl_xor(acc.z, off, 64);
        acc.w += __shfl_xor(acc.w, off, 64);
    }
    float inv = 1.0f / fmaxf((float)(end - start), 1.0f);
    float4 m2 = make_float4(acc.x * inv, acc.y * inv, acc.z * inv, acc.w * inv);
    float4 hn = *(const float4*)&h1[n * 16 + f4 * 4];

    int j0 = slot * 2;
    float4 wl0 = *(const float4*)&W2_l[j0 * 16 + f4 * 4];
    float4 wl1 = *(const float4*)&W2_l[(j0 + 1) * 16 + f4 * 4];
    float4 wr0 = *(const float4*)&W2_r[j0 * 16 + f4 * 4];
    float4 wr1 = *(const float4*)&W2_r[(j0 + 1) * 16 + f4 * 4];

    float pa = m2.x * wl0.x + m2.y * wl0.y + m2.z * wl0.z + m2.w * wl0.w
             + hn.x * wr0.x + hn.y * wr0.y + hn.z * wr0.z + hn.w * wr0.w;
    float pb = m2.x * wl1.x + m2.y * wl1.y + m2.z * wl1.z + m2.w * wl1.w
             + hn.x * wr1.x + hn.y * wr1.y + hn.z * wr1.z + hn.w * wr1.w;
    pa += __shfl_xor(pa, 1, 64); pa += __shfl_xor(pa, 2, 64);
    pb += __shfl_xor(pb, 1, 64); pb += __shfl_xor(pb, 2, 64);

    float h2a = fmaxf(pa + b2_l[j0], 0.f);
    float h2b = fmaxf(pb + b2_l[j0 + 1], 0.f);
    float w = h2a * W_lin[j0] + h2b * W_lin[j0 + 1];
    #pragma unroll
    for (int off = 4; off <= 32; off <<= 1) w += __shfl_xor(w, off, 64);
    if (lane == 0) out[n] = w + b_lin[0];
}

extern "C" void kernel_launch(void* const* d_in, const int* in_sizes, int n_in,
                              void* d_out, int out_size, void* d_ws, size_t ws_size,
                              hipStream_t stream) {
    const float* x       = (const float*)d_in[0];
    const int*   ei      = (const int*)  d_in[1];
    const int*   reg_id  = (const int*)  d_in[2];
    const int*   dep_id  = (const int*)  d_in[3];
    const float* W_feat  = (const float*)d_in[4];
    const float* b_feat  = (const float*)d_in[5];
    const float* reg_emb = (const float*)d_in[6];
    const float* dep_emb = (const float*)d_in[7];
    const float* W1_l    = (const float*)d_in[8];
    const float* b1_l    = (const float*)d_in[9];
    const float* W1_r    = (const float*)d_in[10];
    const float* W2_l    = (const float*)d_in[11];
    const float* b2_l    = (const float*)d_in[12];
    const float* W2_r    = (const float*)d_in[13];
    const float* W_lin   = (const float*)d_in[14];
    const float* b_lin   = (const float*)d_in[15];
    float* out = (float*)d_out;
    float* ws  = (float*)d_ws;

    const int N = N_NODES;
    // workspace (every word fully written each call — no memset needed)
    float* p1 = ws;                              // [N,16]
    float* r1 = ws + 16 * N;                     // [N,16]
    float* h1 = ws + 32 * N;                     // [N,16]
    unsigned int* part  = (unsigned int*)(ws + 48 * N);  // [HB,CNTW] packed u8x4
    unsigned int* drank = part + HB * CNTW;      // [E] (dst<<8)|lrank
    int* csrc  = (int*)(drank + N_EDGES);        // [E]
    unsigned char* bp = (unsigned char*)(csrc + N_EDGES);  // [HB,N] bytes
    int* deg   = (int*)(bp + HB * N_NODES);      // [N]
    int* rowp1 = deg + N;                        // [N]
    int* parts = rowp1 + N;                      // [64]
    // total ≈ 48N + 1.6M + 0.8M + 0.8M + 1.6M + 0.1M words ≈ 29.5 MB

    node1_kernel<<<(N + 63) / 64, 256, 0, stream>>>(
        x, reg_id, dep_id, W_feat, b_feat, reg_emb, dep_emb, W1_l, W1_r, p1, r1);

    hist_lds_kernel<<<HB, 1024, 0, stream>>>(ei, part, drank);
    bp_kernel<<<(N + 255) / 256, 256, 0, stream>>>(part, bp, deg);
    scan1_kernel<<<SCAN_NBLK, SCAN_BLK, 0, stream>>>(deg, rowp1, parts);
    fill_kernel<<<(N_EDGES + 255) / 256, 256, 0, stream>>>(
        ei, drank, rowp1, parts, bp, csrc);

    gather1_kernel<<<(N * 64 + 255) / 256, 256, 0, stream>>>(
        rowp1, parts, csrc, p1, r1, b1_l, h1);

    gather2_kernel<<<(N * 64 + 255) / 256, 256, 0, stream>>>(
        rowp1, parts, csrc, h1, W2_l, b2_l, W2_r, W_lin, b_lin, out);
}